// Round 1
// baseline (477.824 us; speedup 1.0000x reference)
//
#include <hip/hip_runtime.h>
#include <hip/hip_bf16.h>

typedef __bf16 bf16_t;
typedef __bf16 bf16x8 __attribute__((ext_vector_type(8)));
typedef float f32x4 __attribute__((ext_vector_type(4)));

static __device__ __forceinline__ f32x4 mfma16x16x32(bf16x8 a, bf16x8 b, f32x4 c) {
    return __builtin_amdgcn_mfma_f32_16x16x32_bf16(a, b, c, 0, 0, 0);
}

// ---------------------------------------------------------------------------
// GEMM: C[M=8192, N=512] = A[M,512] @ W[512,512]
// AMODE 0: A is f32 (convert to bf16 in staging); AMODE 1: A is bf16.
// EPI 0: write bf16; EPI 1: write f32 with relu * query_mask[row] epilogue.
// block = 256 threads (4 waves), tile 64x64, BK=32.
// ---------------------------------------------------------------------------
template<int AMODE, int EPI>
__global__ __launch_bounds__(256) void gemm512(const void* __restrict__ Aptr,
                                               const float* __restrict__ W,
                                               void* __restrict__ Out,
                                               const int* __restrict__ qmask) {
    __shared__ bf16_t As[64][40];    // 64 rows x 32 k (+8 pad)
    __shared__ bf16_t Bst[64][40];   // 64 cols x 32 k (+8 pad), B transposed

    const int tid  = threadIdx.x;
    const int lane = tid & 63;
    const int wave = tid >> 6;
    const int l15  = lane & 15;
    const int kgrp = lane >> 4;      // 0..3

    const int row0 = blockIdx.x * 64;
    const int col0 = blockIdx.y * 64;

    f32x4 acc[4];
    #pragma unroll
    for (int ct = 0; ct < 4; ++ct) acc[ct] = (f32x4){0.f, 0.f, 0.f, 0.f};

    for (int kb = 0; kb < 512; kb += 32) {
        __syncthreads();
        // --- stage A tile: rows row0..row0+63, k = kb..kb+31 ---
        {
            const int ar = tid >> 2;          // 0..63
            const int ac = (tid & 3) * 8;     // 0,8,16,24
            if (AMODE == 0) {
                const float* Af = (const float*)Aptr + (size_t)(row0 + ar) * 512 + kb + ac;
                float4 x0 = *(const float4*)Af;
                float4 x1 = *(const float4*)(Af + 4);
                As[ar][ac + 0] = (bf16_t)x0.x; As[ar][ac + 1] = (bf16_t)x0.y;
                As[ar][ac + 2] = (bf16_t)x0.z; As[ar][ac + 3] = (bf16_t)x0.w;
                As[ar][ac + 4] = (bf16_t)x1.x; As[ar][ac + 5] = (bf16_t)x1.y;
                As[ar][ac + 6] = (bf16_t)x1.z; As[ar][ac + 7] = (bf16_t)x1.w;
            } else {
                const bf16_t* Ah = (const bf16_t*)Aptr + (size_t)(row0 + ar) * 512 + kb + ac;
                *(bf16x8*)&As[ar][ac] = *(const bf16x8*)Ah;
            }
        }
        // --- stage B tile transposed: Bst[col][k] from W[kb+kk][col0+c] ---
        {
            const int kk = tid >> 3;          // 0..31
            const int cb = (tid & 7) * 8;     // 0..56
            const float* Wf = W + (size_t)(kb + kk) * 512 + col0 + cb;
            float4 y0 = *(const float4*)Wf;
            float4 y1 = *(const float4*)(Wf + 4);
            Bst[cb + 0][kk] = (bf16_t)y0.x; Bst[cb + 1][kk] = (bf16_t)y0.y;
            Bst[cb + 2][kk] = (bf16_t)y0.z; Bst[cb + 3][kk] = (bf16_t)y0.w;
            Bst[cb + 4][kk] = (bf16_t)y1.x; Bst[cb + 5][kk] = (bf16_t)y1.y;
            Bst[cb + 6][kk] = (bf16_t)y1.z; Bst[cb + 7][kk] = (bf16_t)y1.w;
        }
        __syncthreads();

        // --- MFMA: wave owns rows [wave*16, wave*16+16), all 4 col-tiles ---
        bf16x8 af = *(const bf16x8*)&As[wave * 16 + l15][kgrp * 8];
        #pragma unroll
        for (int ct = 0; ct < 4; ++ct) {
            bf16x8 bfr = *(const bf16x8*)&Bst[ct * 16 + l15][kgrp * 8];
            acc[ct] = mfma16x16x32(af, bfr, acc[ct]);
        }
    }

    // --- epilogue: D row = kgrp*4 + j, col = l15 (verified gfx950 C/D map) ---
    #pragma unroll
    for (int ct = 0; ct < 4; ++ct) {
        #pragma unroll
        for (int j = 0; j < 4; ++j) {
            const int r = row0 + wave * 16 + kgrp * 4 + j;
            const int c = col0 + ct * 16 + l15;
            if (EPI == 0) {
                ((bf16_t*)Out)[(size_t)r * 512 + c] = (bf16_t)acc[ct][j];
            } else {
                float v = fmaxf(acc[ct][j], 0.0f) * (float)qmask[r];
                ((float*)Out)[(size_t)r * 512 + c] = v;
            }
        }
    }
}

// ---------------------------------------------------------------------------
// Attention: one block per (h, b, 16-row q tile).
// grid = (64 qtiles, 64 hb). blockIdx.y: h = y>>3, b = y&7.
// Faithful quirks: key-mask row = key_mask[h]; output row = h*1024+s,
// output col = b*64 + d.  Scale = 1/sqrt(512). Full (unskipped) 1024-wide
// rows with exact f32 -1e9 mask adds, like the reference.
// ---------------------------------------------------------------------------
__global__ __launch_bounds__(256) void attn(const bf16_t* __restrict__ qb,
                                            const bf16_t* __restrict__ kbuf,
                                            const bf16_t* __restrict__ vbuf,
                                            const int* __restrict__ key_mask,
                                            bf16_t* __restrict__ attout) {
    __shared__ float  sc[16][1032];   // scores (then probs, f32)
    __shared__ bf16_t pb[16][1032];   // probs bf16 for PV MFMA

    const int tid  = threadIdx.x;
    const int lane = tid & 63;
    const int wave = tid >> 6;
    const int l15  = lane & 15;
    const int kgrp = lane >> 4;

    const int h  = blockIdx.y >> 3;
    const int b  = blockIdx.y & 7;
    const int q0 = blockIdx.x * 16;

    const size_t bS512 = (size_t)b * 1024 * 512;
    const int hoff = h * 64;

    // Q fragments for this 16-row tile (row = l15, k = d dimension)
    const bf16_t* qrow = qb + bS512 + (size_t)(q0 + l15) * 512 + hoff + kgrp * 8;
    bf16x8 aq0 = *(const bf16x8*)qrow;
    bf16x8 aq1 = *(const bf16x8*)(qrow + 32);

    // ---- phase 1: raw scores (Q @ K^T), full 1024 keys ----
    for (int kt = wave; kt < 64; kt += 4) {
        const bf16_t* krow = kbuf + bS512 + (size_t)(kt * 16 + l15) * 512 + hoff + kgrp * 8;
        bf16x8 b0 = *(const bf16x8*)krow;
        bf16x8 b1 = *(const bf16x8*)(krow + 32);
        f32x4 s = (f32x4){0.f, 0.f, 0.f, 0.f};
        s = mfma16x16x32(aq0, b0, s);
        s = mfma16x16x32(aq1, b1, s);
        #pragma unroll
        for (int j = 0; j < 4; ++j) sc[kgrp * 4 + j][kt * 16 + l15] = s[j];
    }
    __syncthreads();

    // ---- phase 2: scale + masks + softmax (16 threads per row) ----
    {
        const int r = tid >> 4;        // 0..15
        const int g = tid & 15;
        const int qglob = q0 + r;
        const float scale = 0.044194173824159216f;  // 1/sqrt(512)
        float mx = -3.0e38f;
        for (int c = g; c < 1024; c += 16) {
            float s = sc[r][c] * scale;
            if (c > qglob) s -= 1.0e9f;                    // causal (exact in f32)
            if (key_mask[h * 1024 + c] == 0) s -= 1.0e9f;  // faithful: row = h
            sc[r][c] = s;
            mx = fmaxf(mx, s);
        }
        #pragma unroll
        for (int o = 1; o < 16; o <<= 1) mx = fmaxf(mx, __shfl_xor(mx, o));
        float sum = 0.f;
        for (int c = g; c < 1024; c += 16) {
            float p = __expf(sc[r][c] - mx);
            sc[r][c] = p;
            sum += p;
        }
        #pragma unroll
        for (int o = 1; o < 16; o <<= 1) sum += __shfl_xor(sum, o);
        const float rinv = 1.0f / sum;
        for (int c = g; c < 1024; c += 16) pb[r][c] = (bf16_t)(sc[r][c] * rinv);
    }
    __syncthreads();

    // ---- phase 3: PV. wave owns d-tile = wave (16 output cols) ----
    f32x4 acc = (f32x4){0.f, 0.f, 0.f, 0.f};
    const int dcol = wave * 16 + l15;
    for (int kbase = 0; kbase < 1024; kbase += 32) {
        bf16x8 pa = *(const bf16x8*)&pb[l15][kbase + kgrp * 8];
        bf16x8 vf;
        const bf16_t* vrow = vbuf + bS512 + (size_t)(kbase + kgrp * 8) * 512 + hoff + dcol;
        #pragma unroll
        for (int j = 0; j < 8; ++j) vf[j] = vrow[(size_t)j * 512];
        acc = mfma16x16x32(pa, vf, acc);
    }
    #pragma unroll
    for (int j = 0; j < 4; ++j) {
        const int qr = q0 + kgrp * 4 + j;
        attout[(size_t)(h * 1024 + qr) * 512 + b * 64 + dcol] = (bf16_t)acc[j];
    }
}

// ---------------------------------------------------------------------------
extern "C" void kernel_launch(void* const* d_in, const int* in_sizes, int n_in,
                              void* d_out, int out_size, void* d_ws, size_t ws_size,
                              hipStream_t stream) {
    const float* query = (const float*)d_in[0];
    const float* key   = (const float*)d_in[1];
    const float* value = (const float*)d_in[2];
    const int*   qmask = (const int*)d_in[3];
    const int*   kmask = (const int*)d_in[4];
    const float* Wq    = (const float*)d_in[5];
    const float* Wk    = (const float*)d_in[6];
    const float* Wv    = (const float*)d_in[7];
    const float* Wo    = (const float*)d_in[8];
    float* out = (float*)d_out;

    const size_t NELEM = (size_t)8 * 1024 * 512;  // 4,194,304
    bf16_t* qb = (bf16_t*)d_ws;
    bf16_t* kb = qb + NELEM;
    bf16_t* vb = kb + NELEM;
    bf16_t* ab = vb + NELEM;

    dim3 blk(256);
    dim3 gg(128, 8);
    gemm512<0, 0><<<gg, blk, 0, stream>>>(query, Wq, qb, nullptr);
    gemm512<0, 0><<<gg, blk, 0, stream>>>(key,   Wk, kb, nullptr);
    gemm512<0, 0><<<gg, blk, 0, stream>>>(value, Wv, vb, nullptr);
    attn<<<dim3(64, 64), blk, 0, stream>>>(qb, kb, vb, kmask, ab);
    gemm512<1, 1><<<gg, blk, 0, stream>>>(ab, Wo, out, qmask);
}

// Round 2
// 181.039 us; speedup vs baseline: 2.6393x; 2.6393x over previous
//
#include <hip/hip_runtime.h>
#include <hip/hip_bf16.h>

typedef __bf16 bf16_t;
typedef __bf16 bf16x8 __attribute__((ext_vector_type(8)));
typedef float f32x4 __attribute__((ext_vector_type(4)));

static __device__ __forceinline__ f32x4 mfma16x16x32(bf16x8 a, bf16x8 b, f32x4 c) {
    return __builtin_amdgcn_mfma_f32_16x16x32_bf16(a, b, c, 0, 0, 0);
}

// ---------------------------------------------------------------------------
// GEMM: C[M=8192, N=512] = A[M,512] @ W[512,512]
// AMODE 0: A is f32 (convert to bf16 in staging); AMODE 1: A is bf16.
// EPI 0: write bf16 row-major; EPI 1: f32 with relu * query_mask[row];
// EPI 2: bf16 transposed per-batch: out[b][col][s] (for V, feeds attention).
// ---------------------------------------------------------------------------
template<int AMODE, int EPI>
__global__ __launch_bounds__(256) void gemm512(const void* __restrict__ Aptr,
                                               const float* __restrict__ W,
                                               void* __restrict__ Out,
                                               const int* __restrict__ qmask) {
    __shared__ bf16_t As[64][40];
    __shared__ bf16_t Bst[64][40];

    const int tid  = threadIdx.x;
    const int lane = tid & 63;
    const int wave = tid >> 6;
    const int l15  = lane & 15;
    const int kgrp = lane >> 4;

    const int row0 = blockIdx.x * 64;
    const int col0 = blockIdx.y * 64;

    f32x4 acc[4];
    #pragma unroll
    for (int ct = 0; ct < 4; ++ct) acc[ct] = (f32x4){0.f, 0.f, 0.f, 0.f};

    for (int kb = 0; kb < 512; kb += 32) {
        __syncthreads();
        {
            const int ar = tid >> 2;
            const int ac = (tid & 3) * 8;
            if (AMODE == 0) {
                const float* Af = (const float*)Aptr + (size_t)(row0 + ar) * 512 + kb + ac;
                float4 x0 = *(const float4*)Af;
                float4 x1 = *(const float4*)(Af + 4);
                As[ar][ac + 0] = (bf16_t)x0.x; As[ar][ac + 1] = (bf16_t)x0.y;
                As[ar][ac + 2] = (bf16_t)x0.z; As[ar][ac + 3] = (bf16_t)x0.w;
                As[ar][ac + 4] = (bf16_t)x1.x; As[ar][ac + 5] = (bf16_t)x1.y;
                As[ar][ac + 6] = (bf16_t)x1.z; As[ar][ac + 7] = (bf16_t)x1.w;
            } else {
                const bf16_t* Ah = (const bf16_t*)Aptr + (size_t)(row0 + ar) * 512 + kb + ac;
                *(bf16x8*)&As[ar][ac] = *(const bf16x8*)Ah;
            }
        }
        {
            const int kk = tid >> 3;
            const int cb = (tid & 7) * 8;
            const float* Wf = W + (size_t)(kb + kk) * 512 + col0 + cb;
            float4 y0 = *(const float4*)Wf;
            float4 y1 = *(const float4*)(Wf + 4);
            Bst[cb + 0][kk] = (bf16_t)y0.x; Bst[cb + 1][kk] = (bf16_t)y0.y;
            Bst[cb + 2][kk] = (bf16_t)y0.z; Bst[cb + 3][kk] = (bf16_t)y0.w;
            Bst[cb + 4][kk] = (bf16_t)y1.x; Bst[cb + 5][kk] = (bf16_t)y1.y;
            Bst[cb + 6][kk] = (bf16_t)y1.z; Bst[cb + 7][kk] = (bf16_t)y1.w;
        }
        __syncthreads();

        bf16x8 af = *(const bf16x8*)&As[wave * 16 + l15][kgrp * 8];
        #pragma unroll
        for (int ct = 0; ct < 4; ++ct) {
            bf16x8 bfr = *(const bf16x8*)&Bst[ct * 16 + l15][kgrp * 8];
            acc[ct] = mfma16x16x32(af, bfr, acc[ct]);
        }
    }

    #pragma unroll
    for (int ct = 0; ct < 4; ++ct) {
        #pragma unroll
        for (int j = 0; j < 4; ++j) {
            const int r = row0 + wave * 16 + kgrp * 4 + j;
            const int c = col0 + ct * 16 + l15;
            if (EPI == 0) {
                ((bf16_t*)Out)[(size_t)r * 512 + c] = (bf16_t)acc[ct][j];
            } else if (EPI == 1) {
                float v = fmaxf(acc[ct][j], 0.0f) * (float)qmask[r];
                ((float*)Out)[(size_t)r * 512 + c] = v;
            } else {
                const int bb = r >> 10;           // batch
                const int ss = r & 1023;          // seq pos
                ((bf16_t*)Out)[((size_t)bb * 512 + c) * 1024 + ss] = (bf16_t)acc[ct][j];
            }
        }
    }
}

// ---------------------------------------------------------------------------
// Flash attention, 1 wave (64 thr) per block; wave owns 32 q-rows of one (h,b).
// grid = (32 qchunks, 64 hb).  K frags read directly from global (row-major),
// V frags from pre-transposed vtb[b][d][s].  Online softmax; faithful -1e9
// additive masks in f32 (exact tie semantics).  Tie rows (all causal-visible
// keys masked, i.e. qw < first-set-bit of key_mask[h]) force full 16 tiles.
// ---------------------------------------------------------------------------
__global__ __launch_bounds__(64) void attn_flash(const bf16_t* __restrict__ qb,
                                                 const bf16_t* __restrict__ kb,
                                                 const bf16_t* __restrict__ vtb,
                                                 const int* __restrict__ key_mask,
                                                 bf16_t* __restrict__ attout) {
    __shared__ bf16_t P[32][68];

    const int lane = threadIdx.x;
    const int l15  = lane & 15;
    const int kgrp = lane >> 4;

    const int h  = blockIdx.y >> 3;
    const int b  = blockIdx.y & 7;
    const int qw = blockIdx.x * 32;

    const size_t bS512 = (size_t)b * 1024 * 512;
    const int hoff = h * 64;
    const int* km = key_mask + h * 1024;

    // first key with mask==1 (tie-row detection)
    int kmv = km[lane];
    unsigned long long bal = __ballot(kmv != 0);
    int first1 = bal ? (__ffsll(bal) - 1) : 64;
    const int ntiles = (qw < first1) ? 16 : ((qw + 95) >> 6);

    // Q fragments (row = l15, k = d)
    bf16x8 aq[2][2];
    #pragma unroll
    for (int rf = 0; rf < 2; ++rf)
        #pragma unroll
        for (int ks = 0; ks < 2; ++ks)
            aq[rf][ks] = *(const bf16x8*)(qb + bS512 + (size_t)(qw + rf * 16 + l15) * 512
                                          + hoff + ks * 32 + kgrp * 8);

    f32x4 O[2][4];
    float m[2][4], l[2][4];
    #pragma unroll
    for (int rf = 0; rf < 2; ++rf) {
        #pragma unroll
        for (int df = 0; df < 4; ++df) O[rf][df] = (f32x4){0.f, 0.f, 0.f, 0.f};
        #pragma unroll
        for (int j = 0; j < 4; ++j) { m[rf][j] = -3.0e38f; l[rf][j] = 0.f; }
    }

    const float scale = 0.044194173824159216f;  // 1/sqrt(512)
    const bf16_t* kbase = kb + bS512 + hoff;
    const bf16_t* vbase = vtb + ((size_t)b * 512 + hoff) * 1024;

    for (int kt = 0; kt < ntiles; ++kt) {
        const int kt0 = kt * 64;

        // ---- QK^T: S[rf][cf], C-layout row=kgrp*4+j, col=l15 ----
        f32x4 S[2][4];
        #pragma unroll
        for (int rf = 0; rf < 2; ++rf)
            #pragma unroll
            for (int cf = 0; cf < 4; ++cf) S[rf][cf] = (f32x4){0.f, 0.f, 0.f, 0.f};

        #pragma unroll
        for (int cf = 0; cf < 4; ++cf) {
            const bf16_t* krow = kbase + (size_t)(kt0 + cf * 16 + l15) * 512 + kgrp * 8;
            bf16x8 bk0 = *(const bf16x8*)krow;
            bf16x8 bk1 = *(const bf16x8*)(krow + 32);
            S[0][cf] = mfma16x16x32(aq[0][0], bk0, S[0][cf]);
            S[0][cf] = mfma16x16x32(aq[0][1], bk1, S[0][cf]);
            S[1][cf] = mfma16x16x32(aq[1][0], bk0, S[1][cf]);
            S[1][cf] = mfma16x16x32(aq[1][1], bk1, S[1][cf]);
        }

        // ---- masks (faithful f32 additive -1e9) + row max ----
        float kmadd[4];
        #pragma unroll
        for (int cf = 0; cf < 4; ++cf)
            kmadd[cf] = (km[kt0 + cf * 16 + l15] == 0) ? 1.0e9f : 0.0f;

        float mx[2][4];
        #pragma unroll
        for (int rf = 0; rf < 2; ++rf)
            #pragma unroll
            for (int j = 0; j < 4; ++j) {
                const int qrow = qw + rf * 16 + kgrp * 4 + j;
                float mj = -3.0e38f;
                #pragma unroll
                for (int cf = 0; cf < 4; ++cf) {
                    float s = S[rf][cf][j] * scale;
                    if (kt0 + cf * 16 + l15 > qrow) s -= 1.0e9f;
                    s -= kmadd[cf];
                    S[rf][cf][j] = s;
                    mj = fmaxf(mj, s);
                }
                mx[rf][j] = mj;
            }
        #pragma unroll
        for (int off = 1; off < 16; off <<= 1)
            #pragma unroll
            for (int rf = 0; rf < 2; ++rf)
                #pragma unroll
                for (int j = 0; j < 4; ++j)
                    mx[rf][j] = fmaxf(mx[rf][j], __shfl_xor(mx[rf][j], off));

        // ---- online update ----
        float fac[2][4], ps[2][4];
        #pragma unroll
        for (int rf = 0; rf < 2; ++rf)
            #pragma unroll
            for (int j = 0; j < 4; ++j) {
                float mn = fmaxf(m[rf][j], mx[rf][j]);
                fac[rf][j] = __expf(m[rf][j] - mn);
                m[rf][j] = mn;
                ps[rf][j] = 0.f;
            }

        #pragma unroll
        for (int rf = 0; rf < 2; ++rf)
            #pragma unroll
            for (int cf = 0; cf < 4; ++cf)
                #pragma unroll
                for (int j = 0; j < 4; ++j) {
                    float p = __expf(S[rf][cf][j] - m[rf][j]);
                    S[rf][cf][j] = p;
                    ps[rf][j] += p;
                }

        #pragma unroll
        for (int off = 1; off < 16; off <<= 1)
            #pragma unroll
            for (int rf = 0; rf < 2; ++rf)
                #pragma unroll
                for (int j = 0; j < 4; ++j)
                    ps[rf][j] += __shfl_xor(ps[rf][j], off);

        #pragma unroll
        for (int rf = 0; rf < 2; ++rf)
            #pragma unroll
            for (int j = 0; j < 4; ++j)
                l[rf][j] = l[rf][j] * fac[rf][j] + ps[rf][j];

        #pragma unroll
        for (int rf = 0; rf < 2; ++rf)
            #pragma unroll
            for (int df = 0; df < 4; ++df)
                #pragma unroll
                for (int j = 0; j < 4; ++j)
                    O[rf][df][j] *= fac[rf][j];

        // ---- P -> LDS (bf16), then read back as A-frags ----
        #pragma unroll
        for (int rf = 0; rf < 2; ++rf)
            #pragma unroll
            for (int cf = 0; cf < 4; ++cf)
                #pragma unroll
                for (int j = 0; j < 4; ++j)
                    P[rf * 16 + kgrp * 4 + j][cf * 16 + l15] = (bf16_t)S[rf][cf][j];

        __syncthreads();

        bf16x8 pa[2][2];
        #pragma unroll
        for (int rf = 0; rf < 2; ++rf)
            #pragma unroll
            for (int ks = 0; ks < 2; ++ks)
                pa[rf][ks] = *(const bf16x8*)&P[rf * 16 + l15][ks * 32 + kgrp * 8];

        // ---- PV: B-frags contiguous from transposed V ----
        #pragma unroll
        for (int df = 0; df < 4; ++df) {
            const bf16_t* vrow = vbase + (size_t)(df * 16 + l15) * 1024 + kt0 + kgrp * 8;
            bf16x8 vf0 = *(const bf16x8*)vrow;
            bf16x8 vf1 = *(const bf16x8*)(vrow + 32);
            O[0][df] = mfma16x16x32(pa[0][0], vf0, O[0][df]);
            O[0][df] = mfma16x16x32(pa[0][1], vf1, O[0][df]);
            O[1][df] = mfma16x16x32(pa[1][0], vf0, O[1][df]);
            O[1][df] = mfma16x16x32(pa[1][1], vf1, O[1][df]);
        }
        __syncthreads();
    }

    // ---- epilogue: O/l -> attout (faithful permuted layout) ----
    #pragma unroll
    for (int rf = 0; rf < 2; ++rf) {
        float rinv[4];
        #pragma unroll
        for (int j = 0; j < 4; ++j) rinv[j] = 1.0f / l[rf][j];
        #pragma unroll
        for (int df = 0; df < 4; ++df)
            #pragma unroll
            for (int j = 0; j < 4; ++j) {
                const int row = qw + rf * 16 + kgrp * 4 + j;
                attout[(size_t)(h * 1024 + row) * 512 + b * 64 + df * 16 + l15] =
                    (bf16_t)(O[rf][df][j] * rinv[j]);
            }
    }
}

// ---------------------------------------------------------------------------
extern "C" void kernel_launch(void* const* d_in, const int* in_sizes, int n_in,
                              void* d_out, int out_size, void* d_ws, size_t ws_size,
                              hipStream_t stream) {
    const float* query = (const float*)d_in[0];
    const float* key   = (const float*)d_in[1];
    const float* value = (const float*)d_in[2];
    const int*   qmask = (const int*)d_in[3];
    const int*   kmask = (const int*)d_in[4];
    const float* Wq    = (const float*)d_in[5];
    const float* Wk    = (const float*)d_in[6];
    const float* Wv    = (const float*)d_in[7];
    const float* Wo    = (const float*)d_in[8];
    float* out = (float*)d_out;

    const size_t NELEM = (size_t)8 * 1024 * 512;
    bf16_t* qb  = (bf16_t*)d_ws;
    bf16_t* kb  = qb + NELEM;
    bf16_t* vtb = kb + NELEM;   // transposed: [b][d(512)][s(1024)]
    bf16_t* ab  = vtb + NELEM;

    dim3 blk(256);
    dim3 gg(128, 8);
    gemm512<0, 0><<<gg, blk, 0, stream>>>(query, Wq, qb, nullptr);
    gemm512<0, 0><<<gg, blk, 0, stream>>>(key,   Wk, kb, nullptr);
    gemm512<0, 2><<<gg, blk, 0, stream>>>(value, Wv, vtb, nullptr);
    attn_flash<<<dim3(32, 64), dim3(64), 0, stream>>>(qb, kb, vtb, kmask, ab);
    gemm512<1, 1><<<gg, blk, 0, stream>>>(ab, Wo, out, qmask);
}

// Round 3
// 139.774 us; speedup vs baseline: 3.4185x; 1.2952x over previous
//
#include <hip/hip_runtime.h>
#include <hip/hip_bf16.h>

typedef __bf16 bf16_t;
typedef __bf16 bf16x8 __attribute__((ext_vector_type(8)));
typedef float f32x4 __attribute__((ext_vector_type(4)));

static __device__ __forceinline__ f32x4 mfma16x16x32(bf16x8 a, bf16x8 b, f32x4 c) {
    return __builtin_amdgcn_mfma_f32_16x16x32_bf16(a, b, c, 0, 0, 0);
}

// ---------------------------------------------------------------------------
// Fused QKV GEMM: for z in {0,1,2}: Out_z[8192,512] = A_z[8192,512] @ W_z[512,512]
// 128x128 tile, 4 waves (2x2), BK=32, reg-staged 2-phase prefetch.
// z<2: bf16 row-major out; z==2: bf16 transposed per-batch out[b][col][s] (V).
// ---------------------------------------------------------------------------
__global__ __launch_bounds__(256, 2) void gemm_qkv(
        const float* __restrict__ Aq, const float* __restrict__ Ak, const float* __restrict__ Av,
        const float* __restrict__ Wq, const float* __restrict__ Wk, const float* __restrict__ Wv,
        bf16_t* __restrict__ Oq, bf16_t* __restrict__ Ok, bf16_t* __restrict__ Ov) {
    __shared__ bf16_t As[128][40];   // [row][k], pad 8 (stride 80B: 2-way = free)
    __shared__ bf16_t Bs[128][40];   // [col][k], pad 8

    const int tid  = threadIdx.x;
    const int lane = tid & 63;
    const int wave = tid >> 6;
    const int l15  = lane & 15;
    const int kgrp = lane >> 4;
    const int wr   = wave >> 1;
    const int wc   = wave & 1;

    const int row0 = blockIdx.x * 128;
    const int col0 = blockIdx.y * 128;
    const int z    = blockIdx.z;

    const float* A = (z == 0) ? Aq : (z == 1) ? Ak : Av;
    const float* W = (z == 0) ? Wq : (z == 1) ? Wk : Wv;

    // staging assignments
    const int ar  = tid >> 1;          // A row 0..127
    const int ach = (tid & 1) * 16;    // A k-half
    const int bc  = tid & 127;         // B col 0..127
    const int bkh = (tid >> 7) * 16;   // B k-half

    f32x4 acc[4][4];
    #pragma unroll
    for (int m = 0; m < 4; ++m)
        #pragma unroll
        for (int n = 0; n < 4; ++n) acc[m][n] = (f32x4){0.f, 0.f, 0.f, 0.f};

    float4 areg[4];
    float  breg[16];
    const float* Abase = A + (size_t)(row0 + ar) * 512 + ach;
    const float* Wbase = W + (size_t)bkh * 512 + col0 + bc;

    // preload k-step 0
    #pragma unroll
    for (int i = 0; i < 4; ++i) areg[i] = *(const float4*)(Abase + i * 4);
    #pragma unroll
    for (int i = 0; i < 16; ++i) breg[i] = Wbase[(size_t)i * 512];

    for (int kb0 = 0; kb0 < 512; kb0 += 32) {
        __syncthreads();   // prev frag reads done
        // regs -> LDS (bf16)
        {
            bf16x8 w0, w1;
            #pragma unroll
            for (int i = 0; i < 4; ++i) { w0[i] = (bf16_t)(&areg[0].x)[i]; w0[i + 4] = (bf16_t)(&areg[1].x)[i]; }
            #pragma unroll
            for (int i = 0; i < 4; ++i) { w1[i] = (bf16_t)(&areg[2].x)[i]; w1[i + 4] = (bf16_t)(&areg[3].x)[i]; }
            *(bf16x8*)&As[ar][ach]     = w0;
            *(bf16x8*)&As[ar][ach + 8] = w1;
            bf16x8 b0, b1;
            #pragma unroll
            for (int i = 0; i < 8; ++i) { b0[i] = (bf16_t)breg[i]; b1[i] = (bf16_t)breg[i + 8]; }
            *(bf16x8*)&Bs[bc][bkh]     = b0;
            *(bf16x8*)&Bs[bc][bkh + 8] = b1;
        }
        __syncthreads();
        // prefetch next k-step while MFMA runs
        if (kb0 + 32 < 512) {
            const float* An = Abase + kb0 + 32;
            #pragma unroll
            for (int i = 0; i < 4; ++i) areg[i] = *(const float4*)(An + i * 4);
            const float* Wn = Wbase + (size_t)(kb0 + 32) * 512;
            #pragma unroll
            for (int i = 0; i < 16; ++i) breg[i] = Wn[(size_t)i * 512];
        }
        bf16x8 af[4], bf[4];
        #pragma unroll
        for (int m = 0; m < 4; ++m) af[m] = *(const bf16x8*)&As[wr * 64 + m * 16 + l15][kgrp * 8];
        #pragma unroll
        for (int n = 0; n < 4; ++n) bf[n] = *(const bf16x8*)&Bs[wc * 64 + n * 16 + l15][kgrp * 8];
        __builtin_amdgcn_s_setprio(1);
        #pragma unroll
        for (int m = 0; m < 4; ++m)
            #pragma unroll
            for (int n = 0; n < 4; ++n)
                acc[m][n] = mfma16x16x32(af[m], bf[n], acc[m][n]);
        __builtin_amdgcn_s_setprio(0);
    }

    bf16_t* O = (z == 0) ? Oq : (z == 1) ? Ok : Ov;
    #pragma unroll
    for (int m = 0; m < 4; ++m)
        #pragma unroll
        for (int j = 0; j < 4; ++j) {
            const int r = row0 + wr * 64 + m * 16 + kgrp * 4 + j;
            #pragma unroll
            for (int n = 0; n < 4; ++n) {
                const int c = col0 + wc * 64 + n * 16 + l15;
                if (z < 2) {
                    O[(size_t)r * 512 + c] = (bf16_t)acc[m][n][j];
                } else {
                    const int bb = r >> 10, ss = r & 1023;
                    O[((size_t)bb * 512 + c) * 1024 + ss] = (bf16_t)acc[m][n][j];
                }
            }
        }
}

// ---------------------------------------------------------------------------
// Output GEMM: out[8192,512] = relu(ab @ Wo) * qmask[row],  f32 out.
// Same 128x128 structure; A is bf16.
// ---------------------------------------------------------------------------
__global__ __launch_bounds__(256, 2) void gemm_out(const bf16_t* __restrict__ Ab,
                                                   const float* __restrict__ W,
                                                   float* __restrict__ Out,
                                                   const int* __restrict__ qmask) {
    __shared__ bf16_t As[128][40];
    __shared__ bf16_t Bs[128][40];

    const int tid  = threadIdx.x;
    const int lane = tid & 63;
    const int wave = tid >> 6;
    const int l15  = lane & 15;
    const int kgrp = lane >> 4;
    const int wr   = wave >> 1;
    const int wc   = wave & 1;

    const int row0 = blockIdx.x * 128;
    const int col0 = blockIdx.y * 128;

    const int ar  = tid >> 1;
    const int ach = (tid & 1) * 16;
    const int bc  = tid & 127;
    const int bkh = (tid >> 7) * 16;

    f32x4 acc[4][4];
    #pragma unroll
    for (int m = 0; m < 4; ++m)
        #pragma unroll
        for (int n = 0; n < 4; ++n) acc[m][n] = (f32x4){0.f, 0.f, 0.f, 0.f};

    bf16x8 areg[2];
    float  breg[16];
    const bf16_t* Abase = Ab + (size_t)(row0 + ar) * 512 + ach;
    const float*  Wbase = W + (size_t)bkh * 512 + col0 + bc;

    areg[0] = *(const bf16x8*)Abase;
    areg[1] = *(const bf16x8*)(Abase + 8);
    #pragma unroll
    for (int i = 0; i < 16; ++i) breg[i] = Wbase[(size_t)i * 512];

    for (int kb0 = 0; kb0 < 512; kb0 += 32) {
        __syncthreads();
        *(bf16x8*)&As[ar][ach]     = areg[0];
        *(bf16x8*)&As[ar][ach + 8] = areg[1];
        {
            bf16x8 b0, b1;
            #pragma unroll
            for (int i = 0; i < 8; ++i) { b0[i] = (bf16_t)breg[i]; b1[i] = (bf16_t)breg[i + 8]; }
            *(bf16x8*)&Bs[bc][bkh]     = b0;
            *(bf16x8*)&Bs[bc][bkh + 8] = b1;
        }
        __syncthreads();
        if (kb0 + 32 < 512) {
            const bf16_t* An = Abase + kb0 + 32;
            areg[0] = *(const bf16x8*)An;
            areg[1] = *(const bf16x8*)(An + 8);
            const float* Wn = Wbase + (size_t)(kb0 + 32) * 512;
            #pragma unroll
            for (int i = 0; i < 16; ++i) breg[i] = Wn[(size_t)i * 512];
        }
        bf16x8 af[4], bf[4];
        #pragma unroll
        for (int m = 0; m < 4; ++m) af[m] = *(const bf16x8*)&As[wr * 64 + m * 16 + l15][kgrp * 8];
        #pragma unroll
        for (int n = 0; n < 4; ++n) bf[n] = *(const bf16x8*)&Bs[wc * 64 + n * 16 + l15][kgrp * 8];
        __builtin_amdgcn_s_setprio(1);
        #pragma unroll
        for (int m = 0; m < 4; ++m)
            #pragma unroll
            for (int n = 0; n < 4; ++n)
                acc[m][n] = mfma16x16x32(af[m], bf[n], acc[m][n]);
        __builtin_amdgcn_s_setprio(0);
    }

    #pragma unroll
    for (int m = 0; m < 4; ++m)
        #pragma unroll
        for (int j = 0; j < 4; ++j) {
            const int r = row0 + wr * 64 + m * 16 + kgrp * 4 + j;
            const float fq = (float)qmask[r];
            #pragma unroll
            for (int n = 0; n < 4; ++n) {
                const int c = col0 + wc * 64 + n * 16 + l15;
                Out[(size_t)r * 512 + c] = fmaxf(acc[m][n][j], 0.0f) * fq;
            }
        }
}

// ---------------------------------------------------------------------------
// Flash attention, 1 wave per block, 32 q-rows.
// grid = (64 hb, 32 chunk): all chunks of one hb share an XCD (id % 8 const).
// chunk = 31 - blockIdx.y  -> heavy (high-qw) blocks dispatch first.
// K double-buffered in regs (compile-time indexed), V loaded pre-softmax.
// ---------------------------------------------------------------------------
__global__ __launch_bounds__(64) void attn_flash(const bf16_t* __restrict__ qb,
                                                 const bf16_t* __restrict__ kb,
                                                 const bf16_t* __restrict__ vtb,
                                                 const int* __restrict__ key_mask,
                                                 bf16_t* __restrict__ attout) {
    __shared__ bf16_t P[32][68];

    const int lane = threadIdx.x;
    const int l15  = lane & 15;
    const int kgrp = lane >> 4;

    const int hb = blockIdx.x;
    const int h  = hb >> 3;
    const int b  = hb & 7;
    const int qw = (31 - (int)blockIdx.y) * 32;

    const size_t bS512 = (size_t)b * 1024 * 512;
    const int hoff = h * 64;
    const int* km = key_mask + h * 1024;

    int kmv = km[lane];
    unsigned long long bal = __ballot(kmv != 0);
    int first1 = bal ? (__ffsll(bal) - 1) : 64;
    const int ntiles = (qw < first1) ? 16 : ((qw + 95) >> 6);

    bf16x8 aq[2][2];
    #pragma unroll
    for (int rf = 0; rf < 2; ++rf)
        #pragma unroll
        for (int ks = 0; ks < 2; ++ks)
            aq[rf][ks] = *(const bf16x8*)(qb + bS512 + (size_t)(qw + rf * 16 + l15) * 512
                                          + hoff + ks * 32 + kgrp * 8);

    f32x4 O[2][4];
    float m[2][4], l[2][4];
    #pragma unroll
    for (int rf = 0; rf < 2; ++rf) {
        #pragma unroll
        for (int df = 0; df < 4; ++df) O[rf][df] = (f32x4){0.f, 0.f, 0.f, 0.f};
        #pragma unroll
        for (int j = 0; j < 4; ++j) { m[rf][j] = -3.0e38f; l[rf][j] = 0.f; }
    }

    const float scale = 0.044194173824159216f;  // 1/sqrt(512)
    const bf16_t* kbase = kb + bS512 + hoff;
    const bf16_t* vbase = vtb + ((size_t)b * 512 + hoff) * 1024;

    bf16x8 kA[4][2], kB[4][2];
    #pragma unroll
    for (int cf = 0; cf < 4; ++cf) {
        const bf16_t* krow = kbase + (size_t)(cf * 16 + l15) * 512 + kgrp * 8;
        kA[cf][0] = *(const bf16x8*)krow;
        kA[cf][1] = *(const bf16x8*)(krow + 32);
    }

    auto tile = [&](int kt, bf16x8 (&kc)[4][2], bf16x8 (&kn)[4][2]) {
        const int kt0 = kt * 64;

        // V for this tile (consumed after softmax -> latency hidden)
        bf16x8 vf[4][2];
        #pragma unroll
        for (int df = 0; df < 4; ++df) {
            const bf16_t* vrow = vbase + (size_t)(df * 16 + l15) * 1024 + kt0 + kgrp * 8;
            vf[df][0] = *(const bf16x8*)vrow;
            vf[df][1] = *(const bf16x8*)(vrow + 32);
        }
        // prefetch next K tile (consumed next iteration)
        if (kt + 1 < ntiles) {
            const int nt0 = kt0 + 64;
            #pragma unroll
            for (int cf = 0; cf < 4; ++cf) {
                const bf16_t* krow = kbase + (size_t)(nt0 + cf * 16 + l15) * 512 + kgrp * 8;
                kn[cf][0] = *(const bf16x8*)krow;
                kn[cf][1] = *(const bf16x8*)(krow + 32);
            }
        }

        f32x4 S[2][4];
        #pragma unroll
        for (int rf = 0; rf < 2; ++rf)
            #pragma unroll
            for (int cf = 0; cf < 4; ++cf) S[rf][cf] = (f32x4){0.f, 0.f, 0.f, 0.f};

        __builtin_amdgcn_s_setprio(1);
        #pragma unroll
        for (int cf = 0; cf < 4; ++cf) {
            S[0][cf] = mfma16x16x32(aq[0][0], kc[cf][0], S[0][cf]);
            S[0][cf] = mfma16x16x32(aq[0][1], kc[cf][1], S[0][cf]);
            S[1][cf] = mfma16x16x32(aq[1][0], kc[cf][0], S[1][cf]);
            S[1][cf] = mfma16x16x32(aq[1][1], kc[cf][1], S[1][cf]);
        }
        __builtin_amdgcn_s_setprio(0);

        float kmadd[4];
        #pragma unroll
        for (int cf = 0; cf < 4; ++cf)
            kmadd[cf] = (km[kt0 + cf * 16 + l15] == 0) ? 1.0e9f : 0.0f;

        const bool needCausal = (kt0 + 63 > qw);
        float mx[2][4];
        #pragma unroll
        for (int rf = 0; rf < 2; ++rf)
            #pragma unroll
            for (int j = 0; j < 4; ++j) {
                const int qrow = qw + rf * 16 + kgrp * 4 + j;
                float mj = -3.0e38f;
                #pragma unroll
                for (int cf = 0; cf < 4; ++cf) {
                    float s = S[rf][cf][j] * scale;
                    if (needCausal && (kt0 + cf * 16 + l15 > qrow)) s -= 1.0e9f;
                    s -= kmadd[cf];
                    S[rf][cf][j] = s;
                    mj = fmaxf(mj, s);
                }
                mx[rf][j] = mj;
            }
        #pragma unroll
        for (int off = 1; off < 16; off <<= 1)
            #pragma unroll
            for (int rf = 0; rf < 2; ++rf)
                #pragma unroll
                for (int j = 0; j < 4; ++j)
                    mx[rf][j] = fmaxf(mx[rf][j], __shfl_xor(mx[rf][j], off));

        float fac[2][4], ps[2][4];
        #pragma unroll
        for (int rf = 0; rf < 2; ++rf)
            #pragma unroll
            for (int j = 0; j < 4; ++j) {
                float mn = fmaxf(m[rf][j], mx[rf][j]);
                fac[rf][j] = __expf(m[rf][j] - mn);
                m[rf][j] = mn;
                ps[rf][j] = 0.f;
            }
        #pragma unroll
        for (int rf = 0; rf < 2; ++rf)
            #pragma unroll
            for (int cf = 0; cf < 4; ++cf)
                #pragma unroll
                for (int j = 0; j < 4; ++j) {
                    float p = __expf(S[rf][cf][j] - m[rf][j]);
                    S[rf][cf][j] = p;
                    ps[rf][j] += p;
                }
        #pragma unroll
        for (int off = 1; off < 16; off <<= 1)
            #pragma unroll
            for (int rf = 0; rf < 2; ++rf)
                #pragma unroll
                for (int j = 0; j < 4; ++j)
                    ps[rf][j] += __shfl_xor(ps[rf][j], off);

        #pragma unroll
        for (int rf = 0; rf < 2; ++rf)
            #pragma unroll
            for (int j = 0; j < 4; ++j)
                l[rf][j] = l[rf][j] * fac[rf][j] + ps[rf][j];
        #pragma unroll
        for (int rf = 0; rf < 2; ++rf)
            #pragma unroll
            for (int df = 0; df < 4; ++df)
                #pragma unroll
                for (int j = 0; j < 4; ++j)
                    O[rf][df][j] *= fac[rf][j];

        #pragma unroll
        for (int rf = 0; rf < 2; ++rf)
            #pragma unroll
            for (int cf = 0; cf < 4; ++cf)
                #pragma unroll
                for (int j = 0; j < 4; ++j)
                    P[rf * 16 + kgrp * 4 + j][cf * 16 + l15] = (bf16_t)S[rf][cf][j];
        __syncthreads();

        bf16x8 pa[2][2];
        #pragma unroll
        for (int rf = 0; rf < 2; ++rf)
            #pragma unroll
            for (int ks = 0; ks < 2; ++ks)
                pa[rf][ks] = *(const bf16x8*)&P[rf * 16 + l15][ks * 32 + kgrp * 8];

        __builtin_amdgcn_s_setprio(1);
        #pragma unroll
        for (int df = 0; df < 4; ++df) {
            O[0][df] = mfma16x16x32(pa[0][0], vf[df][0], O[0][df]);
            O[0][df] = mfma16x16x32(pa[0][1], vf[df][1], O[0][df]);
            O[1][df] = mfma16x16x32(pa[1][0], vf[df][0], O[1][df]);
            O[1][df] = mfma16x16x32(pa[1][1], vf[df][1], O[1][df]);
        }
        __builtin_amdgcn_s_setprio(0);
        __syncthreads();
    };

    for (int kt = 0; kt < ntiles; kt += 2) {
        tile(kt, kA, kB);
        if (kt + 1 < ntiles) tile(kt + 1, kB, kA);
    }

    #pragma unroll
    for (int rf = 0; rf < 2; ++rf) {
        float rinv[4];
        #pragma unroll
        for (int j = 0; j < 4; ++j) rinv[j] = 1.0f / l[rf][j];
        #pragma unroll
        for (int df = 0; df < 4; ++df)
            #pragma unroll
            for (int j = 0; j < 4; ++j) {
                const int row = qw + rf * 16 + kgrp * 4 + j;
                attout[(size_t)(h * 1024 + row) * 512 + b * 64 + df * 16 + l15] =
                    (bf16_t)(O[rf][df][j] * rinv[j]);
            }
    }
}

// ---------------------------------------------------------------------------
extern "C" void kernel_launch(void* const* d_in, const int* in_sizes, int n_in,
                              void* d_out, int out_size, void* d_ws, size_t ws_size,
                              hipStream_t stream) {
    const float* query = (const float*)d_in[0];
    const float* key   = (const float*)d_in[1];
    const float* value = (const float*)d_in[2];
    const int*   qmask = (const int*)d_in[3];
    const int*   kmask = (const int*)d_in[4];
    const float* Wq    = (const float*)d_in[5];
    const float* Wk    = (const float*)d_in[6];
    const float* Wv    = (const float*)d_in[7];
    const float* Wo    = (const float*)d_in[8];
    float* out = (float*)d_out;

    const size_t NELEM = (size_t)8 * 1024 * 512;
    bf16_t* qb  = (bf16_t*)d_ws;
    bf16_t* kb  = qb + NELEM;
    bf16_t* vtb = kb + NELEM;   // [b][d(512)][s(1024)]
    bf16_t* ab  = vtb + NELEM;

    gemm_qkv<<<dim3(64, 4, 3), dim3(256), 0, stream>>>(query, key, value, Wq, Wk, Wv, qb, kb, vtb);
    attn_flash<<<dim3(64, 32), dim3(64), 0, stream>>>(qb, kb, vtb, kmask, ab);
    gemm_out<<<dim3(64, 4), dim3(256), 0, stream>>>(ab, Wo, out, qmask);
}

// Round 4
// 110.005 us; speedup vs baseline: 4.3437x; 1.2706x over previous
//
#include <hip/hip_runtime.h>
#include <hip/hip_bf16.h>

typedef __bf16 bf16_t;
typedef __bf16 bf16x8 __attribute__((ext_vector_type(8)));
typedef float f32x4 __attribute__((ext_vector_type(4)));

static __device__ __forceinline__ f32x4 mfma16x16x32(bf16x8 a, bf16x8 b, f32x4 c) {
    return __builtin_amdgcn_mfma_f32_16x16x32_bf16(a, b, c, 0, 0, 0);
}

// ---------------------------------------------------------------------------
// Fused QKV GEMM: for z in {0,1,2}: Out_z[8192,512] = A_z[8192,512] @ W_z[512,512]
// 128x128 tile, 4 waves (2x2), BK=32, reg-staged 2-phase prefetch.
// z<2: bf16 row-major out; z==2: bf16 transposed per-batch out[b][col][s] (V).
// ---------------------------------------------------------------------------
__global__ __launch_bounds__(256, 2) void gemm_qkv(
        const float* __restrict__ Aq, const float* __restrict__ Ak, const float* __restrict__ Av,
        const float* __restrict__ Wq, const float* __restrict__ Wk, const float* __restrict__ Wv,
        bf16_t* __restrict__ Oq, bf16_t* __restrict__ Ok, bf16_t* __restrict__ Ov) {
    __shared__ bf16_t As[128][40];
    __shared__ bf16_t Bs[128][40];

    const int tid  = threadIdx.x;
    const int lane = tid & 63;
    const int wave = tid >> 6;
    const int l15  = lane & 15;
    const int kgrp = lane >> 4;
    const int wr   = wave >> 1;
    const int wc   = wave & 1;

    const int row0 = blockIdx.x * 128;
    const int col0 = blockIdx.y * 128;
    const int z    = blockIdx.z;

    const float* A = (z == 0) ? Aq : (z == 1) ? Ak : Av;
    const float* W = (z == 0) ? Wq : (z == 1) ? Wk : Wv;

    const int ar  = tid >> 1;
    const int ach = (tid & 1) * 16;
    const int bc  = tid & 127;
    const int bkh = (tid >> 7) * 16;

    f32x4 acc[4][4];
    #pragma unroll
    for (int m = 0; m < 4; ++m)
        #pragma unroll
        for (int n = 0; n < 4; ++n) acc[m][n] = (f32x4){0.f, 0.f, 0.f, 0.f};

    float4 areg[4];
    float  breg[16];
    const float* Abase = A + (size_t)(row0 + ar) * 512 + ach;
    const float* Wbase = W + (size_t)bkh * 512 + col0 + bc;

    #pragma unroll
    for (int i = 0; i < 4; ++i) areg[i] = *(const float4*)(Abase + i * 4);
    #pragma unroll
    for (int i = 0; i < 16; ++i) breg[i] = Wbase[(size_t)i * 512];

    for (int kb0 = 0; kb0 < 512; kb0 += 32) {
        __syncthreads();
        {
            bf16x8 w0, w1;
            #pragma unroll
            for (int i = 0; i < 4; ++i) { w0[i] = (bf16_t)(&areg[0].x)[i]; w0[i + 4] = (bf16_t)(&areg[1].x)[i]; }
            #pragma unroll
            for (int i = 0; i < 4; ++i) { w1[i] = (bf16_t)(&areg[2].x)[i]; w1[i + 4] = (bf16_t)(&areg[3].x)[i]; }
            *(bf16x8*)&As[ar][ach]     = w0;
            *(bf16x8*)&As[ar][ach + 8] = w1;
            bf16x8 b0, b1;
            #pragma unroll
            for (int i = 0; i < 8; ++i) { b0[i] = (bf16_t)breg[i]; b1[i] = (bf16_t)breg[i + 8]; }
            *(bf16x8*)&Bs[bc][bkh]     = b0;
            *(bf16x8*)&Bs[bc][bkh + 8] = b1;
        }
        __syncthreads();
        if (kb0 + 32 < 512) {
            const float* An = Abase + kb0 + 32;
            #pragma unroll
            for (int i = 0; i < 4; ++i) areg[i] = *(const float4*)(An + i * 4);
            const float* Wn = Wbase + (size_t)(kb0 + 32) * 512;
            #pragma unroll
            for (int i = 0; i < 16; ++i) breg[i] = Wn[(size_t)i * 512];
        }
        bf16x8 af[4], bf[4];
        #pragma unroll
        for (int m = 0; m < 4; ++m) af[m] = *(const bf16x8*)&As[wr * 64 + m * 16 + l15][kgrp * 8];
        #pragma unroll
        for (int n = 0; n < 4; ++n) bf[n] = *(const bf16x8*)&Bs[wc * 64 + n * 16 + l15][kgrp * 8];
        __builtin_amdgcn_s_setprio(1);
        #pragma unroll
        for (int m = 0; m < 4; ++m)
            #pragma unroll
            for (int n = 0; n < 4; ++n)
                acc[m][n] = mfma16x16x32(af[m], bf[n], acc[m][n]);
        __builtin_amdgcn_s_setprio(0);
    }

    bf16_t* O = (z == 0) ? Oq : (z == 1) ? Ok : Ov;
    #pragma unroll
    for (int m = 0; m < 4; ++m)
        #pragma unroll
        for (int j = 0; j < 4; ++j) {
            const int r = row0 + wr * 64 + m * 16 + kgrp * 4 + j;
            #pragma unroll
            for (int n = 0; n < 4; ++n) {
                const int c = col0 + wc * 64 + n * 16 + l15;
                if (z < 2) {
                    O[(size_t)r * 512 + c] = (bf16_t)acc[m][n][j];
                } else {
                    const int bb = r >> 10, ss = r & 1023;
                    O[((size_t)bb * 512 + c) * 1024 + ss] = (bf16_t)acc[m][n][j];
                }
            }
        }
}

// ---------------------------------------------------------------------------
// Output GEMM: out[8192,512] = relu(ab @ Wo) * qmask[row],  f32 out.
// ---------------------------------------------------------------------------
__global__ __launch_bounds__(256, 2) void gemm_out(const bf16_t* __restrict__ Ab,
                                                   const float* __restrict__ W,
                                                   float* __restrict__ Out,
                                                   const int* __restrict__ qmask) {
    __shared__ bf16_t As[128][40];
    __shared__ bf16_t Bs[128][40];

    const int tid  = threadIdx.x;
    const int lane = tid & 63;
    const int wave = tid >> 6;
    const int l15  = lane & 15;
    const int kgrp = lane >> 4;
    const int wr   = wave >> 1;
    const int wc   = wave & 1;

    const int row0 = blockIdx.x * 128;
    const int col0 = blockIdx.y * 128;

    const int ar  = tid >> 1;
    const int ach = (tid & 1) * 16;
    const int bc  = tid & 127;
    const int bkh = (tid >> 7) * 16;

    f32x4 acc[4][4];
    #pragma unroll
    for (int m = 0; m < 4; ++m)
        #pragma unroll
        for (int n = 0; n < 4; ++n) acc[m][n] = (f32x4){0.f, 0.f, 0.f, 0.f};

    bf16x8 areg[2];
    float  breg[16];
    const bf16_t* Abase = Ab + (size_t)(row0 + ar) * 512 + ach;
    const float*  Wbase = W + (size_t)bkh * 512 + col0 + bc;

    areg[0] = *(const bf16x8*)Abase;
    areg[1] = *(const bf16x8*)(Abase + 8);
    #pragma unroll
    for (int i = 0; i < 16; ++i) breg[i] = Wbase[(size_t)i * 512];

    for (int kb0 = 0; kb0 < 512; kb0 += 32) {
        __syncthreads();
        *(bf16x8*)&As[ar][ach]     = areg[0];
        *(bf16x8*)&As[ar][ach + 8] = areg[1];
        {
            bf16x8 b0, b1;
            #pragma unroll
            for (int i = 0; i < 8; ++i) { b0[i] = (bf16_t)breg[i]; b1[i] = (bf16_t)breg[i + 8]; }
            *(bf16x8*)&Bs[bc][bkh]     = b0;
            *(bf16x8*)&Bs[bc][bkh + 8] = b1;
        }
        __syncthreads();
        if (kb0 + 32 < 512) {
            const bf16_t* An = Abase + kb0 + 32;
            areg[0] = *(const bf16x8*)An;
            areg[1] = *(const bf16x8*)(An + 8);
            const float* Wn = Wbase + (size_t)(kb0 + 32) * 512;
            #pragma unroll
            for (int i = 0; i < 16; ++i) breg[i] = Wn[(size_t)i * 512];
        }
        bf16x8 af[4], bf[4];
        #pragma unroll
        for (int m = 0; m < 4; ++m) af[m] = *(const bf16x8*)&As[wr * 64 + m * 16 + l15][kgrp * 8];
        #pragma unroll
        for (int n = 0; n < 4; ++n) bf[n] = *(const bf16x8*)&Bs[wc * 64 + n * 16 + l15][kgrp * 8];
        __builtin_amdgcn_s_setprio(1);
        #pragma unroll
        for (int m = 0; m < 4; ++m)
            #pragma unroll
            for (int n = 0; n < 4; ++n)
                acc[m][n] = mfma16x16x32(af[m], bf[n], acc[m][n]);
        __builtin_amdgcn_s_setprio(0);
    }

    #pragma unroll
    for (int m = 0; m < 4; ++m)
        #pragma unroll
        for (int j = 0; j < 4; ++j) {
            const int r = row0 + wr * 64 + m * 16 + kgrp * 4 + j;
            const float fq = (float)qmask[r];
            #pragma unroll
            for (int n = 0; n < 4; ++n) {
                const int c = col0 + wc * 64 + n * 16 + l15;
                Out[(size_t)r * 512 + c] = fmaxf(acc[m][n][j], 0.0f) * fq;
            }
        }
}

// ---------------------------------------------------------------------------
// Flash attention, split-K across 4 waves. Block = 256 thr, 32 q-rows of one
// (h,b); wave w processes K-tiles {w, w+4, ...}, keeps private (m,l,O);
// block-level exact softmax merge at the end through LDS.
// grid = (64 hb, 32 chunk): id%8 = b -> per-XCD batch locality.
// chunk = 31 - blockIdx.y -> heavy blocks dispatch first.
// ---------------------------------------------------------------------------
__global__ __launch_bounds__(256, 3) void attn_flash(const bf16_t* __restrict__ qb,
                                                     const bf16_t* __restrict__ kb,
                                                     const bf16_t* __restrict__ vtb,
                                                     const int* __restrict__ key_mask,
                                                     bf16_t* __restrict__ attout) {
    __shared__ char shbuf[34816];
    // phase A: per-wave P tiles (17408 B used)
    bf16_t (*P)[32][68] = (bf16_t(*)[32][68])shbuf;
    // phase B (after barrier): merge buffers
    float (*Omg)[32][66] = (float(*)[32][66])shbuf;          // 33792 B
    float* mmg = (float*)(shbuf + 33792);                    // 4*32 floats
    float* lmg = (float*)(shbuf + 33792 + 512);              // 4*32 floats

    const int tid  = threadIdx.x;
    const int lane = tid & 63;
    const int w    = tid >> 6;     // wave id = K-slice
    const int l15  = lane & 15;
    const int kgrp = lane >> 4;

    const int hb = blockIdx.x;
    const int h  = hb >> 3;
    const int b  = hb & 7;
    const int qw = (31 - (int)blockIdx.y) * 32;

    const size_t bS512 = (size_t)b * 1024 * 512;
    const int hoff = h * 64;
    const int* km = key_mask + h * 1024;

    int kmv = km[lane];
    unsigned long long bal = __ballot(kmv != 0);
    int first1 = bal ? (__ffsll(bal) - 1) : 64;
    const int ntiles = (qw < first1) ? 16 : ((qw + 95) >> 6);

    bf16x8 aq[2][2];
    #pragma unroll
    for (int rf = 0; rf < 2; ++rf)
        #pragma unroll
        for (int ks = 0; ks < 2; ++ks)
            aq[rf][ks] = *(const bf16x8*)(qb + bS512 + (size_t)(qw + rf * 16 + l15) * 512
                                          + hoff + ks * 32 + kgrp * 8);

    f32x4 O[2][4];
    float m[2][4], l[2][4];
    #pragma unroll
    for (int rf = 0; rf < 2; ++rf) {
        #pragma unroll
        for (int df = 0; df < 4; ++df) O[rf][df] = (f32x4){0.f, 0.f, 0.f, 0.f};
        #pragma unroll
        for (int j = 0; j < 4; ++j) { m[rf][j] = -3.0e38f; l[rf][j] = 0.f; }
    }

    const float scale = 0.044194173824159216f;  // 1/sqrt(512)
    const bf16_t* kbase = kb + bS512 + hoff;
    const bf16_t* vbase = vtb + ((size_t)b * 512 + hoff) * 1024;

    for (int kt = w; kt < ntiles; kt += 4) {
        const int kt0 = kt * 64;

        // ---- QK^T ----
        f32x4 S[2][4];
        #pragma unroll
        for (int rf = 0; rf < 2; ++rf)
            #pragma unroll
            for (int cf = 0; cf < 4; ++cf) S[rf][cf] = (f32x4){0.f, 0.f, 0.f, 0.f};

        __builtin_amdgcn_s_setprio(1);
        #pragma unroll
        for (int cf = 0; cf < 4; ++cf) {
            const bf16_t* krow = kbase + (size_t)(kt0 + cf * 16 + l15) * 512 + kgrp * 8;
            bf16x8 bk0 = *(const bf16x8*)krow;
            bf16x8 bk1 = *(const bf16x8*)(krow + 32);
            S[0][cf] = mfma16x16x32(aq[0][0], bk0, S[0][cf]);
            S[0][cf] = mfma16x16x32(aq[0][1], bk1, S[0][cf]);
            S[1][cf] = mfma16x16x32(aq[1][0], bk0, S[1][cf]);
            S[1][cf] = mfma16x16x32(aq[1][1], bk1, S[1][cf]);
        }
        __builtin_amdgcn_s_setprio(0);

        // ---- masks (faithful f32 additive -1e9) + per-lane max ----
        float kmadd[4];
        #pragma unroll
        for (int cf = 0; cf < 4; ++cf)
            kmadd[cf] = (km[kt0 + cf * 16 + l15] == 0) ? 1.0e9f : 0.0f;

        float mx[2][4];
        #pragma unroll
        for (int rf = 0; rf < 2; ++rf)
            #pragma unroll
            for (int j = 0; j < 4; ++j) {
                const int qrow = qw + rf * 16 + kgrp * 4 + j;
                float mj = -3.0e38f;
                #pragma unroll
                for (int cf = 0; cf < 4; ++cf) {
                    float s = S[rf][cf][j] * scale;
                    if (kt0 + cf * 16 + l15 > qrow) s -= 1.0e9f;
                    s -= kmadd[cf];
                    S[rf][cf][j] = s;
                    mj = fmaxf(mj, s);
                }
                mx[rf][j] = mj;
            }
        #pragma unroll
        for (int off = 1; off < 16; off <<= 1)
            #pragma unroll
            for (int rf = 0; rf < 2; ++rf)
                #pragma unroll
                for (int j = 0; j < 4; ++j)
                    mx[rf][j] = fmaxf(mx[rf][j], __shfl_xor(mx[rf][j], off));

        // ---- online update (l kept as per-lane partial; no sum reduce) ----
        float fac[2][4];
        #pragma unroll
        for (int rf = 0; rf < 2; ++rf)
            #pragma unroll
            for (int j = 0; j < 4; ++j) {
                float mn = fmaxf(m[rf][j], mx[rf][j]);
                fac[rf][j] = __expf(m[rf][j] - mn);
                m[rf][j] = mn;
            }
        #pragma unroll
        for (int rf = 0; rf < 2; ++rf)
            #pragma unroll
            for (int j = 0; j < 4; ++j) {
                float ps = 0.f;
                #pragma unroll
                for (int cf = 0; cf < 4; ++cf) {
                    float p = __expf(S[rf][cf][j] - m[rf][j]);
                    S[rf][cf][j] = p;
                    ps += p;
                }
                l[rf][j] = l[rf][j] * fac[rf][j] + ps;
            }
        #pragma unroll
        for (int rf = 0; rf < 2; ++rf)
            #pragma unroll
            for (int df = 0; df < 4; ++df)
                #pragma unroll
                for (int j = 0; j < 4; ++j)
                    O[rf][df][j] *= fac[rf][j];

        // ---- P -> per-wave LDS tile, wave-local wait (no block barrier) ----
        #pragma unroll
        for (int rf = 0; rf < 2; ++rf)
            #pragma unroll
            for (int cf = 0; cf < 4; ++cf)
                #pragma unroll
                for (int j = 0; j < 4; ++j)
                    P[w][rf * 16 + kgrp * 4 + j][cf * 16 + l15] = (bf16_t)S[rf][cf][j];
        asm volatile("s_waitcnt lgkmcnt(0)" ::: "memory");

        bf16x8 pa[2][2];
        #pragma unroll
        for (int rf = 0; rf < 2; ++rf)
            #pragma unroll
            for (int ks = 0; ks < 2; ++ks)
                pa[rf][ks] = *(const bf16x8*)&P[w][rf * 16 + l15][ks * 32 + kgrp * 8];

        // ---- PV ----
        __builtin_amdgcn_s_setprio(1);
        #pragma unroll
        for (int df = 0; df < 4; ++df) {
            const bf16_t* vrow = vbase + (size_t)(df * 16 + l15) * 1024 + kt0 + kgrp * 8;
            bf16x8 vf0 = *(const bf16x8*)vrow;
            bf16x8 vf1 = *(const bf16x8*)(vrow + 32);
            O[0][df] = mfma16x16x32(pa[0][0], vf0, O[0][df]);
            O[0][df] = mfma16x16x32(pa[0][1], vf1, O[0][df]);
            O[1][df] = mfma16x16x32(pa[1][0], vf0, O[1][df]);
            O[1][df] = mfma16x16x32(pa[1][1], vf1, O[1][df]);
        }
        __builtin_amdgcn_s_setprio(0);
    }

    // ---- merge phase ----
    __syncthreads();   // all waves done with P region

    // reduce per-lane l partials across the 16-lane row group
    #pragma unroll
    for (int rf = 0; rf < 2; ++rf)
        #pragma unroll
        for (int j = 0; j < 4; ++j) {
            float lv = l[rf][j];
            #pragma unroll
            for (int off = 1; off < 16; off <<= 1) lv += __shfl_xor(lv, off);
            l[rf][j] = lv;
        }

    #pragma unroll
    for (int rf = 0; rf < 2; ++rf)
        #pragma unroll
        for (int df = 0; df < 4; ++df)
            #pragma unroll
            for (int j = 0; j < 4; ++j)
                Omg[w][rf * 16 + kgrp * 4 + j][df * 16 + l15] = O[rf][df][j];
    if (l15 == 0) {
        #pragma unroll
        for (int rf = 0; rf < 2; ++rf)
            #pragma unroll
            for (int j = 0; j < 4; ++j) {
                mmg[w * 32 + rf * 16 + kgrp * 4 + j] = m[rf][j];
                lmg[w * 32 + rf * 16 + kgrp * 4 + j] = l[rf][j];
            }
    }
    __syncthreads();

    {
        const int r  = tid >> 3;        // 0..31
        const int c0 = (tid & 7) * 8;   // 0..56
        float m0 = mmg[r], m1 = mmg[32 + r], m2 = mmg[64 + r], m3 = mmg[96 + r];
        float M = fmaxf(fmaxf(m0, m1), fmaxf(m2, m3));
        float f0 = __expf(m0 - M), f1 = __expf(m1 - M);
        float f2 = __expf(m2 - M), f3 = __expf(m3 - M);
        float ls = lmg[r] * f0 + lmg[32 + r] * f1 + lmg[64 + r] * f2 + lmg[96 + r] * f3;
        float inv = 1.0f / ls;
        bf16_t outv[8];
        #pragma unroll
        for (int i = 0; i < 8; ++i) {
            float acc = Omg[0][r][c0 + i] * f0 + Omg[1][r][c0 + i] * f1
                      + Omg[2][r][c0 + i] * f2 + Omg[3][r][c0 + i] * f3;
            outv[i] = (bf16_t)(acc * inv);
        }
        *(bf16x8*)&attout[(size_t)(h * 1024 + qw + r) * 512 + b * 64 + c0] = *(bf16x8*)outv;
    }
}

// ---------------------------------------------------------------------------
extern "C" void kernel_launch(void* const* d_in, const int* in_sizes, int n_in,
                              void* d_out, int out_size, void* d_ws, size_t ws_size,
                              hipStream_t stream) {
    const float* query = (const float*)d_in[0];
    const float* key   = (const float*)d_in[1];
    const float* value = (const float*)d_in[2];
    const int*   qmask = (const int*)d_in[3];
    const int*   kmask = (const int*)d_in[4];
    const float* Wq    = (const float*)d_in[5];
    const float* Wk    = (const float*)d_in[6];
    const float* Wv    = (const float*)d_in[7];
    const float* Wo    = (const float*)d_in[8];
    float* out = (float*)d_out;

    const size_t NELEM = (size_t)8 * 1024 * 512;
    bf16_t* qb  = (bf16_t*)d_ws;
    bf16_t* kb  = qb + NELEM;
    bf16_t* vtb = kb + NELEM;   // [b][d(512)][s(1024)]
    bf16_t* ab  = vtb + NELEM;

    gemm_qkv<<<dim3(64, 4, 3), dim3(256), 0, stream>>>(query, key, value, Wq, Wk, Wv, qb, kb, vtb);
    attn_flash<<<dim3(64, 32), dim3(256), 0, stream>>>(qb, kb, vtb, kmask, ab);
    gemm_out<<<dim3(64, 4), dim3(256), 0, stream>>>(ab, Wo, out, qmask);
}